// Round 7
// baseline (295.609 us; speedup 1.0000x reference)
//
#include <hip/hip_runtime.h>
#include <hip/hip_bf16.h>
#include <math.h>

typedef __bf16 bf16;
typedef __bf16 bf16x8 __attribute__((ext_vector_type(8)));
typedef float  f32x4  __attribute__((ext_vector_type(4)));

#define N_PTS 32768

// ---------------- init: zero per-expert counters ----------------
__global__ void k_init(int* counts) {
    if (threadIdx.x < 8) counts[threadIdx.x] = 0;
}

// ---------------- per-point: expert argmin, fg test, compaction, zero non-fg outputs ----------------
// Inputs f32 (probe-verified R6); OUTPUT IS F32 (R6 post-mortem: 0.515625 = bf16 color bits read as f32).
__global__ void k_point(const float* __restrict__ pts, float* __restrict__ out,
                        int* __restrict__ counts, unsigned short* __restrict__ idxlist) {
    int n = blockIdx.x * 256 + threadIdx.x;
    if (n >= N_PTS) return;
    float px = pts[3*n+0], py = pts[3*n+1], pz = pts[3*n+2];
    int e = 0; float best = 3.4e38f;
    #pragma unroll
    for (int i = 0; i < 4; ++i)
        #pragma unroll
        for (int j = 0; j < 2; ++j) {
            float cx = j ? 50.f : -50.f, cy = -75.f + 50.f * i;
            float dx = px - cx, dy = py - cy, dz = pz - 20.f;
            float d = dx*dx + dy*dy + dz*dz;
            if (d < best) { best = d; e = i*2 + j; }   // first-min tie-break = np argmin
        }
    bool fg = (px >= -80.f && px <= 80.f && py >= -80.f && py <= 80.f &&
               pz >= -4.f  && pz <= 44.f);
    if (fg) {
        int slot = atomicAdd(&counts[e], 1);
        idxlist[e * N_PTS + slot] = (unsigned short)n;
    } else {
        out[n] = 0.f;
        out[N_PTS + 3*n + 0] = 0.f;
        out[N_PTS + 3*n + 1] = 0.f;
        out[N_PTS + 3*n + 2] = 0.f;
    }
}

// ---------------- fused MLP, 32 points/block, 4 waves, MFMA 16x16x32 bf16 ----------------
__device__ __forceinline__ f32x4 mfma16(bf16x8 a, bf16x8 b, f32x4 c) {
    return __builtin_amdgcn_mfma_f32_16x16x32_bf16(a, b, c, 0, 0, 0);
}

__device__ __forceinline__ void zacc(f32x4 acc[2][4]) {
    #pragma unroll
    for (int i = 0; i < 2; ++i)
        #pragma unroll
        for (int j = 0; j < 4; ++j) acc[i][j] = (f32x4){0.f, 0.f, 0.f, 0.f};
}

// A: LDS activations [32][astr] bf16 (rows m = points)
// W: original f32 weights, [k][n] row-major, row stride ldn (pre-offset by expert)
// B-frag: lane(l16,quad) needs W[wk0+kA+j][n], j=0..7 -> 8 strided f32 loads + cvt
template<int NS, bool GUARD>
__device__ __forceinline__ void gemm_g(f32x4 acc[2][4], const bf16* A, int astr,
                                       const float* __restrict__ W, int ldn, int wk0, int Klim,
                                       int nbase, int l16, int quad) {
    #pragma unroll
    for (int s = 0; s < NS; ++s) {
        int kA = s * 32 + quad * 8;
        bf16x8 a0 = *(const bf16x8*)(A + (size_t)(l16)      * astr + kA);
        bf16x8 a1 = *(const bf16x8*)(A + (size_t)(16 + l16) * astr + kA);
        #pragma unroll
        for (int nt = 0; nt < 4; ++nt) {
            int n = nbase + nt * 16 + l16;
            const float* wp = W + (size_t)(wk0 + kA) * ldn + n;
            bf16x8 b;
            #pragma unroll
            for (int j = 0; j < 8; ++j) {
                float wv = 0.f;
                if (!GUARD || (wk0 + kA + j < Klim)) wv = wp[(size_t)j * ldn];
                b[j] = (bf16)wv;
            }
            acc[0][nt] = mfma16(a0, b, acc[0][nt]);
            acc[1][nt] = mfma16(a1, b, acc[1][nt]);
        }
    }
}

__device__ __forceinline__ void epi(f32x4 acc[2][4], const float* bias, bool dorelu,
                                    bf16* dst, int dstr, int nbase, int l16, int quad) {
    #pragma unroll
    for (int nt = 0; nt < 4; ++nt) {
        float bv = bias[nbase + nt * 16 + l16];
        #pragma unroll
        for (int mt = 0; mt < 2; ++mt) {
            #pragma unroll
            for (int r = 0; r < 4; ++r) {
                float v = acc[mt][nt][r] + bv;
                v = fminf(fmaxf(v, -64.f), 64.f);   // defensive; exact-64 output = NaN canary
                if (dorelu) v = fmaxf(v, 0.f);
                // C/D layout: col(n)=lane&15, row(m)=quad*4+r  [measured m89/m91]
                dst[(size_t)(mt * 16 + quad * 4 + r) * dstr + nbase + nt * 16 + l16] = (bf16)v;
            }
        }
    }
}

__global__ __launch_bounds__(256, 2)
void k_main(const int* __restrict__ counts, const unsigned short* __restrict__ idxlist,
            const float* __restrict__ pts, const float* __restrict__ dirs,
            const float* __restrict__ app_embed, const int* __restrict__ aidx,
            const float* __restrict__ W0, const float* __restrict__ b0,
            const float* __restrict__ W_pre, const float* __restrict__ b_pre,
            const float* __restrict__ Wskip, const float* __restrict__ bskip,
            const float* __restrict__ W_post, const float* __restrict__ b_post,
            const float* __restrict__ Wd, const float* __restrict__ bd,
            const float* __restrict__ Wf, const float* __restrict__ bf_,
            const float* __restrict__ Wc1, const float* __restrict__ bc1,
            const float* __restrict__ Wc2, const float* __restrict__ bc2,
            float* __restrict__ out) {
    // strides: every ds_read_b128 16B-aligned; row aliasing <= 2-way (free, m136)
    __shared__ bf16 xa [32 * 264];   // activations
    __shared__ bf16 x0l[32 * 136];   // x0 tile
    __shared__ bf16 del[32 * 48];    // dir enc
    __shared__ int  gidx[32];
    __shared__ int  aid[32];

    const int e    = blockIdx.x & 7;       // expert -> XCD affinity for weight L2 locality
    const int tile = blockIdx.x >> 3;
    const int cnt  = counts[e];
    if (tile * 32 >= cnt) return;
    const int t = threadIdx.x;
    const int lane = t & 63, wv = t >> 6;
    const int l16 = lane & 15, quad = lane >> 4;
    const int nbase = wv * 64;

    if (t < 32) {
        int i = tile * 32 + t;
        int g = (i < cnt) ? (int)idxlist[e * N_PTS + i] : -1;
        gidx[t] = g;
        aid[t]  = (g >= 0) ? aidx[g] : 0;
    }
    __syncthreads();
    { // stage x0 = [p(3), posenc(60), app(48), 0-pad] and de = [d(3), posenc(24), 0-pad]
        int row = t >> 3, g = gidx[row];
        float c0 = 0.f, c1 = 0.f, c2 = 0.f, d0 = 0.f, d1 = 0.f, d2 = 0.f;
        if (g >= 0) {
            c0 = pts[3*g+0];  c1 = pts[3*g+1];  c2 = pts[3*g+2];
            d0 = dirs[3*g+0]; d1 = dirs[3*g+1]; d2 = dirs[3*g+2];
        }
        int ai = aid[row];
        #pragma unroll
        for (int i = 0; i < 16; ++i) {
            int col = (t & 7) * 16 + i;
            float v = 0.f;
            if (g >= 0) {
                if (col < 3) {
                    v = (col == 0) ? c0 : (col == 1) ? c1 : c2;
                } else if (col < 63) {
                    int q = col - 3, fi = q / 6, d = q % 6, ax = (d < 3) ? d : (d - 3);
                    float p = (ax == 0) ? c0 : (ax == 1) ? c1 : c2;
                    float f = (float)exp2((double)fi * (10.0 / 9.0)); // np 2**linspace(0,10,10)
                    v = (d < 3) ? sinf(f * p) : cosf(f * p);
                } else if (col < 111) {
                    v = app_embed[((size_t)(e * 1000 + ai)) * 48 + (col - 63)];
                }
            }
            x0l[row * 136 + col] = (bf16)v;
        }
        #pragma unroll
        for (int i = 0; i < 4; ++i) {
            int col = (t & 7) * 4 + i;
            float v = 0.f;
            if (g >= 0) {
                if (col < 3) {
                    v = (col == 0) ? d0 : (col == 1) ? d1 : d2;
                } else if (col < 27) {
                    int q = col - 3, fi = q / 6, d = q % 6, ax = (d < 3) ? d : (d - 3);
                    float p = (ax == 0) ? d0 : (ax == 1) ? d1 : d2;
                    float f = (float)exp2((double)fi * (4.0 / 3.0));  // np 2**linspace(0,4,4)
                    v = (d < 3) ? sinf(f * p) : cosf(f * p);
                }
            }
            del[row * 48 + col] = (bf16)v;
        }
    }
    __syncthreads();

    f32x4 acc[2][4];
    // L0: x0(111) @ W0[111][256] -> relu -> xa
    zacc(acc);
    gemm_g<4, true>(acc, x0l, 136, W0 + (size_t)e * 28416, 256, 0, 111, nbase, l16, quad);
    __syncthreads();
    epi(acc, b0 + e * 256, true, xa, 264, nbase, l16, quad);
    __syncthreads();
    // 3 pre layers
    for (int i = 0; i < 3; ++i) {
        zacc(acc);
        gemm_g<8, false>(acc, xa, 264, W_pre + (size_t)(e * 3 + i) * 65536, 256, 0, 256, nbase, l16, quad);
        __syncthreads();
        epi(acc, b_pre + (e * 3 + i) * 256, true, xa, 264, nbase, l16, quad);
        __syncthreads();
    }
    // skip layer: [x(256), x0(111)] @ Wskip[367][256]
    zacc(acc);
    gemm_g<8, false>(acc, xa,  264, Wskip + (size_t)e * 93952, 256, 0,   367, nbase, l16, quad);
    gemm_g<4, true >(acc, x0l, 136, Wskip + (size_t)e * 93952, 256, 256, 367, nbase, l16, quad);
    __syncthreads();
    epi(acc, bskip + e * 256, true, xa, 264, nbase, l16, quad);
    __syncthreads();
    // 3 post layers
    for (int i = 0; i < 3; ++i) {
        zacc(acc);
        gemm_g<8, false>(acc, xa, 264, W_post + (size_t)(e * 3 + i) * 65536, 256, 0, 256, nbase, l16, quad);
        __syncthreads();
        epi(acc, b_post + (e * 3 + i) * 256, true, xa, 264, nbase, l16, quad);
        __syncthreads();
    }
    // density = relu(x @ Wd + bd): 8 lanes/point, shuffle-reduce -> F32 out
    {
        int m = t >> 3, p = t & 7;
        const bf16*  xr = xa + (size_t)m * 264;
        const float* wd = Wd + e * 256;
        float s = 0.f;
        for (int k = p * 32; k < p * 32 + 32; ++k) s += (float)xr[k] * wd[k];
        s += __shfl_down(s, 4, 8);
        s += __shfl_down(s, 2, 8);
        s += __shfl_down(s, 1, 8);
        if (p == 0) {
            int g = gidx[m];
            if (g >= 0) out[g] = fminf(fmaxf(s + bd[e], 0.f), 64.f);
        }
    }
    // feat = x @ Wf + bf (NO relu) -> xa
    zacc(acc);
    gemm_g<8, false>(acc, xa, 264, Wf + (size_t)e * 65536, 256, 0, 256, nbase, l16, quad);
    __syncthreads();
    epi(acc, bf_ + e * 256, false, xa, 264, nbase, l16, quad);
    __syncthreads();
    // h = relu([feat(256), de(27)] @ Wc1[283][128] + bc1): waves 0,1
    if (wv < 2) {
        zacc(acc);
        gemm_g<8, false>(acc, xa,  264, Wc1 + (size_t)e * 36224, 128, 0,   283, nbase, l16, quad);
        gemm_g<1, true >(acc, del, 48,  Wc1 + (size_t)e * 36224, 128, 256, 283, nbase, l16, quad);
    }
    __syncthreads();
    if (wv < 2) epi(acc, bc1 + e * 128, true, xa, 264, nbase, l16, quad);
    __syncthreads();
    // color = sigmoid(h @ Wc2 + bc2) -> F32 out
    if (t < 96) {
        int m = t & 31, c = t >> 5;
        int g = gidx[m];
        if (g >= 0) {
            const bf16*  xr = xa + (size_t)m * 264;
            const float* w  = Wc2 + e * 384 + c;
            float s = 0.f;
            for (int k = 0; k < 128; ++k) s += (float)xr[k] * w[k * 3];
            s += bc2[e * 3 + c];
            s = fminf(fmaxf(s, -30.f), 30.f);
            out[N_PTS + 3 * g + c] = 1.f / (1.f + expf(-s));
        }
    }
}

extern "C" void kernel_launch(void* const* d_in, const int* in_sizes, int n_in,
                              void* d_out, int out_size, void* d_ws, size_t ws_size,
                              hipStream_t stream) {
    // All real-valued inputs f32 (probe-verified), appearance_idx int32, OUTPUT f32.
    const float* points    = (const float*)d_in[0];
    const float* viewdirs  = (const float*)d_in[1];
    const int*   aidx      = (const int*)  d_in[2];
    const float* app_embed = (const float*)d_in[3];
    const float* W0        = (const float*)d_in[4];
    const float* b0        = (const float*)d_in[5];
    const float* W_pre     = (const float*)d_in[6];
    const float* b_pre     = (const float*)d_in[7];
    const float* Wskip     = (const float*)d_in[8];
    const float* bskip     = (const float*)d_in[9];
    const float* W_post    = (const float*)d_in[10];
    const float* b_post    = (const float*)d_in[11];
    const float* Wd        = (const float*)d_in[12];
    const float* bd        = (const float*)d_in[13];
    const float* Wf        = (const float*)d_in[14];
    const float* bf_       = (const float*)d_in[15];
    const float* Wc1       = (const float*)d_in[16];
    const float* bc1       = (const float*)d_in[17];
    const float* Wc2       = (const float*)d_in[18];
    const float* bc2       = (const float*)d_in[19];
    float* out = (float*)d_out;
    (void)viewdirs; (void)in_sizes; (void)n_in; (void)out_size; (void)ws_size;

    // workspace: counts (32 B @ off 0) + ushort idxlist (512 KB) ~= 513 KB
    char* ws = (char*)d_ws;
    int*            counts  = (int*)ws;
    unsigned short* idxlist = (unsigned short*)(ws + 256);

    hipLaunchKernelGGL(k_init,  dim3(1), dim3(64), 0, stream, counts);
    hipLaunchKernelGGL(k_point, dim3(N_PTS / 256), dim3(256), 0, stream,
                       points, out, counts, idxlist);
    hipLaunchKernelGGL(k_main, dim3(8 * (N_PTS / 32)), dim3(256), 0, stream,
                       counts, idxlist, points, (const float*)d_in[1], app_embed, aidx,
                       W0, b0, W_pre, b_pre, Wskip, bskip, W_post, b_post,
                       Wd, bd, Wf, bf_, Wc1, bc1, Wc2, bc2, out);
}